// Round 5
// baseline (4039.750 us; speedup 1.0000x reference)
//
#include <hip/hip_runtime.h>
#include <math.h>
#include <stdint.h>

// Keep compiler contraction OFF globally: the ONLY fusions are my explicit
// fmaf() calls, which model LLVM's contract-FMF fusion on the XLA CPU host.
#pragma clang fp contract(off)

#define N_PIX 802816          // 16*1*224*224
#define T_WIN 100
#define KN_MAX 96             // Knuth subkey chain length
#define RJ_MAX 48             // rejection subkey chain length (G ~ 8)
#define G_SLOT (KN_MAX * 2 + RJ_MAX * 4)   // ws u32 index of global max-iter

// ---------------- threefry2x32 (JAX rotation/injection schedule) -------------
__device__ __forceinline__ void tf2x32(uint32_t k0, uint32_t k1,
                                       uint32_t x0, uint32_t x1,
                                       uint32_t &o0, uint32_t &o1) {
  uint32_t ks2 = k0 ^ k1 ^ 0x1BD11BDAu;
  x0 += k0; x1 += k1;
#define TF_R(r) { x0 += x1; x1 = (x1 << (r)) | (x1 >> (32 - (r))); x1 ^= x0; }
  TF_R(13) TF_R(15) TF_R(26) TF_R(6)
  x0 += k1;  x1 += ks2 + 1u;
  TF_R(17) TF_R(29) TF_R(16) TF_R(24)
  x0 += ks2; x1 += k0 + 2u;
  TF_R(13) TF_R(15) TF_R(26) TF_R(6)
  x0 += k0;  x1 += k1 + 3u;
  TF_R(17) TF_R(29) TF_R(16) TF_R(24)
  x0 += k1;  x1 += ks2 + 4u;
  TF_R(13) TF_R(15) TF_R(26) TF_R(6)
  x0 += ks2; x1 += k0 + 5u;
#undef TF_R
  o0 = x0; o1 = x1;
}

// Partitionable random_bits, 32-bit: hash (hi=0, lo=p), fold bits1 ^ bits2.
__device__ __forceinline__ uint32_t unif_bits(uint32_t s0, uint32_t s1, uint32_t p) {
  uint32_t a, b;
  tf2x32(s0, s1, 0u, p, a, b);
  return a ^ b;
}

__device__ __forceinline__ float bits_to_unit(uint32_t bits) {
  return __uint_as_float(0x3f800000u | (bits >> 9)) - 1.0f;
}

// ---------------- XLA CPU f32 log (GenerateVF32Log / Eigen plog), with
// contract-FMF fusion as LLVM's x86 backend performs it (fadd's mul-operand-0
// fuses; standalone muls stay rounded). ---------------------------------------
__device__ __forceinline__ float xla_logf(float xin) {
#pragma clang fp contract(off)
  if (xin == 0.0f) return __uint_as_float(0xff800000u);           // -inf
  if (!(xin > 0.0f)) return __uint_as_float(0x7fc00000u);         // nan
  float x = fmaxf(xin, __uint_as_float(0x00800000u));             // flush denorm
  uint32_t ib = __float_as_uint(x);
  float e = (float)((int)(ib >> 23) - 126);                       // cvt(E-127)+1
  ib = (ib & 0x007fffffu) | 0x3f000000u;                          // [0.5,1)
  x = __uint_as_float(ib);
  float tmp = 0.0f, eadj = 0.0f;
  if (x < (float)0.707106781186547524) { tmp = x; eadj = 1.0f; }
  x = x - 1.0f;
  e = e - eadj;
  x = x + tmp;
  float x2 = x * x;
  float x3 = x2 * x;
  // pmadd -> fma under contract FMF
  float y  = fmaf((float)7.0376836292e-2,  x, (float)-1.1514610310e-1);
  float y1 = fmaf((float)-1.2420140846e-1, x, (float)1.4249322787e-1);
  float y2 = fmaf((float)2.0000714765e-1,  x, (float)-2.4999993993e-1);
  y  = fmaf(y,  x, (float)1.1676998740e-1);
  y1 = fmaf(y1, x, (float)-1.6668057665e-1);
  y2 = fmaf(y2, x, (float)3.3333331174e-1);
  y  = fmaf(y, x3, y1);
  y  = fmaf(y, x3, y2);
  // Eigen tail: y=y*x3; y1=e*q1; tmp2=x2*half; y=y+y1; x=x-tmp2; y2=e*q2;
  //             x=x+y; x=x+y2   -- fused per DAGCombiner rules:
  float eq1 = e * (float)-2.12194440e-4;   // standalone mul (operand-1 of fadd)
  y = fmaf(y, x3, eq1);                    // fadd(mul,mul): operand-0 fuses
  x = fmaf(-x2, 0.5f, x);                  // fsub(x, mul) -> fnmadd
  x = x + y;                               // fadd of two fma results: stays add
  x = fmaf(e, (float)0.693359375, x);      // fadd(x, mul) -> fma (operand-1)
  return x;
}

// XLA EmitLog1p: |x| < 1e-4 ? fma(-0.5,x,1)*x : log(x+1)
__device__ __forceinline__ float xla_log1pf(float w) {
#pragma clang fp contract(off)
  if (fabsf(w) < (float)1e-4) return fmaf(-0.5f, w, 1.0f) * w;
  return xla_logf(w + 1.0f);
}

// XLA Lgamma (Lanczos g=7), non-reflection branch (x >= 1 in all live uses).
// Denominators (z+i)+1: exact for integer z (no fusion sites). Final log_y:
// fma(inner, log_t, log_sqrt_2pi) + log(sum) under contract.
__device__ __forceinline__ float xla_lgammaf_pos(float x) {
#pragma clang fp contract(off)
  const float kBase = (float)0.99999999999980993227684700473478;
  const float c0 = (float)676.520368121885098567009190444019;
  const float c1 = (float)-1259.13921672240287047156078755283;
  const float c2 = (float)771.3234287776530788486528258894;
  const float c3 = (float)-176.61502916214059906584551354;
  const float c4 = (float)12.507343278686904814458936853;
  const float c5 = (float)-0.13857109526572011689554707;
  const float c6 = (float)9.984369578019570859563e-6;
  const float c7 = (float)1.50563273514931155834e-7;
  const float kLogSqrtTwoPi = (float)0.91893853320467274178032973640562;
  const float kGPlusHalf = 7.5f;
  const float kLogGPlusHalf = (float)2.0149030205422647065; // log(7.5)
  float z = x - 1.0f;
  float sum = kBase;
  sum = sum + c0 / ((z + 0.0f) + 1.0f);
  sum = sum + c1 / ((z + 1.0f) + 1.0f);
  sum = sum + c2 / ((z + 2.0f) + 1.0f);
  sum = sum + c3 / ((z + 3.0f) + 1.0f);
  sum = sum + c4 / ((z + 4.0f) + 1.0f);
  sum = sum + c5 / ((z + 5.0f) + 1.0f);
  sum = sum + c6 / ((z + 6.0f) + 1.0f);
  sum = sum + c7 / ((z + 7.0f) + 1.0f);
  float t = kGPlusHalf + z;
  float log_t = kLogGPlusHalf + xla_log1pf(z / kGPlusHalf);
  float log_y = fmaf((z + 0.5f) - t / log_t, log_t, kLogSqrtTwoPi) + xla_logf(sum);
  return log_y;
}

// ---------------- rejection sampler shared pieces ----------------------------
struct RejConst {
  float lam, neg_lam, log_lam, aa, bb, inv_alpha, v_r, two_a;
};

__device__ __forceinline__ RejConst make_rej(float lam) {
  RejConst rc;
  rc.lam = lam;
  rc.neg_lam = -lam;
  rc.log_lam = xla_logf(lam);
  float sq = (float)sqrt((double)lam);                  // CR f32 sqrt
  rc.bb = fmaf(2.53f, sq, (float)0.931);                // 0.931 + 2.53*sqrt -> fma
  rc.aa = fmaf((float)0.02483, rc.bb, (float)-0.059);   // -0.059 + 0.02483*b -> fma
  rc.inv_alpha = (float)1.1239 + (float)1.1328 / (rc.bb - (float)3.4);  // div+add: unfused
  rc.v_r = (float)0.9277 - (float)3.6224 / (rc.bb - 2.0f);              // div+sub: unfused
  rc.two_a = 2.0f * rc.aa;
  return rc;
}

// One rejection iteration j at position p. Returns accept; writes k.
__device__ __forceinline__ bool rej_step(const RejConst& rc,
                                         const uint32_t* __restrict__ rj,
                                         int j, uint32_t p, float& kf_out) {
  float u = bits_to_unit(unif_bits(rj[4 * j + 0], rj[4 * j + 1], p)) - 0.5f;
  float v = bits_to_unit(unif_bits(rj[4 * j + 2], rj[4 * j + 3], p));
  float u_sh = 0.5f - fabsf(u);
  // ((2a/u_sh + b)*u + lam) -> fma; +0.43 stays separate add
  float kf = floorf(fmaf(rc.two_a / u_sh + rc.bb, u, rc.lam) + (float)0.43);
  kf_out = kf;
  if ((u_sh >= (float)0.07) && (v <= rc.v_r)) return true;          // accept1
  if ((kf < 0.0f) || ((u_sh < (float)0.013) && (v > u_sh))) return false; // reject
  float sv = xla_logf((v * rc.inv_alpha) / ((rc.aa / (u_sh * u_sh)) + rc.bb));
  // -lam + k*log_lam -> fma(k, log_lam, -lam); then - lgamma
  float tv = fmaf(kf, rc.log_lam, rc.neg_lam) - xla_lgammaf_pos(kf + 1.0f);
  return sv <= tv;                                                  // accept2
}

// lam_rejection per lax.select: knuth-masked (lam<10 or lam==0) -> 1e5f
__device__ __forceinline__ float lam_rejection(float uimg) {
  float lam = 100000.0f;
  if (uimg != 0.0f) {
    float l = 1.0f / uimg;
    if (!(l < 10.0f)) lam = l;
  }
  return lam;
}

// ---------------- prologue: subkey chains + G slot ---------------------------
__global__ void chain_init(uint32_t* __restrict__ ws) {
  if (blockIdx.x == 0) {
    if (threadIdx.x != 0) return;
    ws[G_SLOT] = 0u;
    uint32_t r0 = 0u, r1 = 42u;  // jax.random.key(42) -> (0,42)
    for (int j = 0; j < KN_MAX; ++j) {
      uint32_t s0, s1, n0, n1;
      tf2x32(r0, r1, 0u, 1u, s0, s1);
      tf2x32(r0, r1, 0u, 0u, n0, n1);
      ws[2 * j] = s0; ws[2 * j + 1] = s1;
      r0 = n0; r1 = n1;
    }
  } else {
    if (threadIdx.x != 0) return;
    uint32_t c0 = 0u, c1 = 42u;
    for (int j = 0; j < RJ_MAX; ++j) {
      uint32_t a0, a1, b0, b1, n0, n1;
      tf2x32(c0, c1, 0u, 1u, a0, a1);
      tf2x32(c0, c1, 0u, 2u, b0, b1);
      tf2x32(c0, c1, 0u, 0u, n0, n1);
      uint32_t base = KN_MAX * 2 + 4 * j;
      ws[base + 0] = a0; ws[base + 1] = a1; ws[base + 2] = b0; ws[base + 3] = b1;
      c0 = n0; c1 = n1;
    }
  }
}

// ---------------- pass 1: G = max over ALL (T,N) positions of first-accept ---
__global__ void __launch_bounds__(256)
rej_gmax(const float* __restrict__ img, const uint32_t* __restrict__ ws_chains,
         uint32_t* __restrict__ gmax) {
  __shared__ uint32_t rj[RJ_MAX * 4];
  __shared__ uint32_t red[256];
  for (int i = threadIdx.x; i < RJ_MAX * 4; i += 256)
    rj[i] = ws_chains[KN_MAX * 2 + i];
  __syncthreads();

  int n = blockIdx.x * 256 + threadIdx.x;
  uint32_t mymax = 1;
  if (n < N_PIX) {
    RejConst rc = make_rej(lam_rejection(img[n]));
    for (int t = 0; t < T_WIN; ++t) {
      uint32_t p = (uint32_t)t * (uint32_t)N_PIX + (uint32_t)n;
      int j = 0;
      for (; j < RJ_MAX; ++j) {
        float kf;
        if (rej_step(rc, rj, j, p, kf)) break;
      }
      uint32_t fa = (uint32_t)(j < RJ_MAX ? j + 1 : RJ_MAX);
      if (fa > mymax) mymax = fa;
    }
  }
  red[threadIdx.x] = mymax;
  __syncthreads();
  for (int s2 = 128; s2 > 0; s2 >>= 1) {
    if ((int)threadIdx.x < s2) {
      uint32_t o = red[threadIdx.x + s2];
      if (o > red[threadIdx.x]) red[threadIdx.x] = o;
    }
    __syncthreads();
  }
  if (threadIdx.x == 0) atomicMax((unsigned int*)gmax, red[0]);
}

// ---------------- pass 2: one thread per pixel -------------------------------
__global__ void __launch_bounds__(256)
spike_main(const float* __restrict__ img, int* __restrict__ out,
           const uint32_t* __restrict__ chains) {
  __shared__ uint32_t sh[KN_MAX * 2 + RJ_MAX * 4];
  __shared__ int shG;
  for (int i = threadIdx.x; i < KN_MAX * 2 + RJ_MAX * 4; i += 256) sh[i] = chains[i];
  if (threadIdx.x == 0) shG = (int)chains[G_SLOT];
  __syncthreads();
  const uint32_t* kn = sh;
  const uint32_t* rj = sh + KN_MAX * 2;
  const int G = shG;

  int n = blockIdx.x * 256 + threadIdx.x;
  if (n >= N_PIX) return;
  float uimg = img[n];
  unsigned long long bm0 = 0ull, bm1 = 0ull;  // spike bitmap: bit (s-1), s in [1,100]

  if (uimg != 0.0f) {
    float lam = 1.0f / uimg;
    int s = 0;
    if (lam < 10.0f) {
      // ---- Knuth (k freezes once log_prod <= -lam: first-exit is exact) ----
      float neg_lam = -lam;
      for (int t = 0; t < T_WIN; ++t) {
        uint32_t p = (uint32_t)t * (uint32_t)N_PIX + (uint32_t)n;
        int k = 0;
        float lp = 0.0f;
        int j = 0;
        while (lp > neg_lam && j < KN_MAX) {
          ++k;
          float u = bits_to_unit(unif_bits(kn[2 * j], kn[2 * j + 1], p));
          lp = lp + xla_logf(u);
          ++j;
        }
        int iv = k - 1;
        if (iv == 0) iv = 1;       // nz & interval==0 -> 1
        s += iv;
        if (s > T_WIN) break;      // integer sums <= 100 are exact in any order
        if (s <= 64) bm0 |= 1ull << (s - 1); else bm1 |= 1ull << (s - 65);
      }
    } else {
      // ---- Hormann rejection: k_out = k of the LAST accept within G iters ----
      RejConst rc = make_rej(lam);
      for (int t = 0; t < T_WIN; ++t) {
        uint32_t p = (uint32_t)t * (uint32_t)N_PIX + (uint32_t)n;
        float kf_acc = -1.0f;
        for (int j = 0; j < G; ++j) {
          float kf;
          if (rej_step(rc, rj, j, p, kf)) kf_acc = kf;  // overwrite: last accept
        }
        int iv = (kf_acc >= 102.0f) ? 102 : (int)kf_acc; // values >100 all dead
        if (iv == 0) iv = 1;
        s += iv;
        if (s > T_WIN) break;
        if (s <= 64) bm0 |= 1ull << (s - 1); else bm1 |= 1ull << (s - 65);
      }
    }
  }

  // Column write: int32 0/1 (bool output); coalesced; zero-fills poisoned d_out.
  size_t base = (size_t)n;
  for (int t = 0; t < 64; ++t)
    out[base + (size_t)t * N_PIX] = (int)((bm0 >> t) & 1ull);
  for (int t = 64; t < T_WIN; ++t)
    out[base + (size_t)t * N_PIX] = (int)((bm1 >> (t - 64)) & 1ull);
}

extern "C" void kernel_launch(void* const* d_in, const int* in_sizes, int n_in,
                              void* d_out, int out_size, void* d_ws, size_t ws_size,
                              hipStream_t stream) {
  const float* img = (const float*)d_in[0];
  int* out = (int*)d_out;
  uint32_t* ws = (uint32_t*)d_ws;  // needs 1540 B
  hipLaunchKernelGGL(chain_init, dim3(2), dim3(64), 0, stream, ws);
  hipLaunchKernelGGL(rej_gmax, dim3(N_PIX / 256), dim3(256), 0, stream,
                     img, ws, ws + G_SLOT);
  hipLaunchKernelGGL(spike_main, dim3(N_PIX / 256), dim3(256), 0, stream,
                     img, out, ws);
}

// Round 6
// 1635.454 us; speedup vs baseline: 2.4701x; 2.4701x over previous
//
#include <hip/hip_runtime.h>
#include <math.h>
#include <stdint.h>

// Keep compiler contraction OFF globally: the ONLY fusions are my explicit
// fmaf() calls, which model LLVM's contract-FMF fusion on the XLA CPU host.
#pragma clang fp contract(off)

#define N_PIX 802816          // 16*1*224*224
#define T_WIN 100
#define KN_MAX 96             // Knuth subkey chain length
#define RJ_MAX 48             // rejection subkey chain length (G ~ 10)
#define G_SLOT (KN_MAX * 2 + RJ_MAX * 4)   // ws u32 index of global max-iter

// ---------------- threefry2x32 (JAX rotation/injection schedule) -------------
__device__ __forceinline__ void tf2x32(uint32_t k0, uint32_t k1,
                                       uint32_t x0, uint32_t x1,
                                       uint32_t &o0, uint32_t &o1) {
  uint32_t ks2 = k0 ^ k1 ^ 0x1BD11BDAu;
  x0 += k0; x1 += k1;
#define TF_R(r) { x0 += x1; x1 = (x1 << (r)) | (x1 >> (32 - (r))); x1 ^= x0; }
  TF_R(13) TF_R(15) TF_R(26) TF_R(6)
  x0 += k1;  x1 += ks2 + 1u;
  TF_R(17) TF_R(29) TF_R(16) TF_R(24)
  x0 += ks2; x1 += k0 + 2u;
  TF_R(13) TF_R(15) TF_R(26) TF_R(6)
  x0 += k0;  x1 += k1 + 3u;
  TF_R(17) TF_R(29) TF_R(16) TF_R(24)
  x0 += k1;  x1 += ks2 + 4u;
  TF_R(13) TF_R(15) TF_R(26) TF_R(6)
  x0 += ks2; x1 += k0 + 5u;
#undef TF_R
  o0 = x0; o1 = x1;
}

// Partitionable random_bits, 32-bit: hash (hi=0, lo=p), fold bits1 ^ bits2.
__device__ __forceinline__ uint32_t unif_bits(uint32_t s0, uint32_t s1, uint32_t p) {
  uint32_t a, b;
  tf2x32(s0, s1, 0u, p, a, b);
  return a ^ b;
}

__device__ __forceinline__ float bits_to_unit(uint32_t bits) {
  return __uint_as_float(0x3f800000u | (bits >> 9)) - 1.0f;
}

// ---------------- XLA CPU f32 log (GenerateVF32Log / Eigen plog), with
// contract-FMF fusion exactly as verified in round 5. -------------------------
__device__ __forceinline__ float xla_logf(float xin) {
#pragma clang fp contract(off)
  if (xin == 0.0f) return __uint_as_float(0xff800000u);           // -inf
  if (!(xin > 0.0f)) return __uint_as_float(0x7fc00000u);         // nan
  float x = fmaxf(xin, __uint_as_float(0x00800000u));             // flush denorm
  uint32_t ib = __float_as_uint(x);
  float e = (float)((int)(ib >> 23) - 126);                       // cvt(E-127)+1
  ib = (ib & 0x007fffffu) | 0x3f000000u;                          // [0.5,1)
  x = __uint_as_float(ib);
  float tmp = 0.0f, eadj = 0.0f;
  if (x < (float)0.707106781186547524) { tmp = x; eadj = 1.0f; }
  x = x - 1.0f;
  e = e - eadj;
  x = x + tmp;
  float x2 = x * x;
  float x3 = x2 * x;
  float y  = fmaf((float)7.0376836292e-2,  x, (float)-1.1514610310e-1);
  float y1 = fmaf((float)-1.2420140846e-1, x, (float)1.4249322787e-1);
  float y2 = fmaf((float)2.0000714765e-1,  x, (float)-2.4999993993e-1);
  y  = fmaf(y,  x, (float)1.1676998740e-1);
  y1 = fmaf(y1, x, (float)-1.6668057665e-1);
  y2 = fmaf(y2, x, (float)3.3333331174e-1);
  y  = fmaf(y, x3, y1);
  y  = fmaf(y, x3, y2);
  float eq1 = e * (float)-2.12194440e-4;   // standalone mul
  y = fmaf(y, x3, eq1);                    // fadd(mul,mul): operand-0 fuses
  x = fmaf(-x2, 0.5f, x);                  // fsub(x, mul) -> fnmadd
  x = x + y;                               // add of two fma results
  x = fmaf(e, (float)0.693359375, x);      // fadd(x, mul) -> fma
  return x;
}

// XLA EmitLog1p: |x| < 1e-4 ? fma(-0.5,x,1)*x : log(x+1)
__device__ __forceinline__ float xla_log1pf(float w) {
#pragma clang fp contract(off)
  if (fabsf(w) < (float)1e-4) return fmaf(-0.5f, w, 1.0f) * w;
  return xla_logf(w + 1.0f);
}

// XLA Lgamma (Lanczos g=7), non-reflection branch (x >= 1 in all live uses).
__device__ __forceinline__ float xla_lgammaf_pos(float x) {
#pragma clang fp contract(off)
  const float kBase = (float)0.99999999999980993227684700473478;
  const float c0 = (float)676.520368121885098567009190444019;
  const float c1 = (float)-1259.13921672240287047156078755283;
  const float c2 = (float)771.3234287776530788486528258894;
  const float c3 = (float)-176.61502916214059906584551354;
  const float c4 = (float)12.507343278686904814458936853;
  const float c5 = (float)-0.13857109526572011689554707;
  const float c6 = (float)9.984369578019570859563e-6;
  const float c7 = (float)1.50563273514931155834e-7;
  const float kLogSqrtTwoPi = (float)0.91893853320467274178032973640562;
  const float kGPlusHalf = 7.5f;
  const float kLogGPlusHalf = (float)2.0149030205422647065; // log(7.5)
  float z = x - 1.0f;
  float sum = kBase;
  sum = sum + c0 / ((z + 0.0f) + 1.0f);
  sum = sum + c1 / ((z + 1.0f) + 1.0f);
  sum = sum + c2 / ((z + 2.0f) + 1.0f);
  sum = sum + c3 / ((z + 3.0f) + 1.0f);
  sum = sum + c4 / ((z + 4.0f) + 1.0f);
  sum = sum + c5 / ((z + 5.0f) + 1.0f);
  sum = sum + c6 / ((z + 6.0f) + 1.0f);
  sum = sum + c7 / ((z + 7.0f) + 1.0f);
  float t = kGPlusHalf + z;
  float log_t = kLogGPlusHalf + xla_log1pf(z / kGPlusHalf);
  float log_y = fmaf((z + 0.5f) - t / log_t, log_t, kLogSqrtTwoPi) + xla_logf(sum);
  return log_y;
}

// ---------------- rejection sampler shared pieces ----------------------------
struct RejConst {
  float lam, neg_lam, log_lam, aa, bb, inv_alpha, v_r, two_a;
};

__device__ __forceinline__ RejConst make_rej(float lam) {
  RejConst rc;
  rc.lam = lam;
  rc.neg_lam = -lam;
  rc.log_lam = xla_logf(lam);
  float sq = (float)sqrt((double)lam);                  // CR f32 sqrt
  rc.bb = fmaf(2.53f, sq, (float)0.931);
  rc.aa = fmaf((float)0.02483, rc.bb, (float)-0.059);
  rc.inv_alpha = (float)1.1239 + (float)1.1328 / (rc.bb - (float)3.4);
  rc.v_r = (float)0.9277 - (float)3.6224 / (rc.bb - 2.0f);
  rc.two_a = 2.0f * rc.aa;
  return rc;
}

// One rejection iteration with chain entry ch at position p. Same numerics
// as round 5 (byte-identical).
__device__ __forceinline__ bool rej_step4(const RejConst& rc, uint4 ch,
                                          uint32_t p, float& kf_out) {
  float u = bits_to_unit(unif_bits(ch.x, ch.y, p)) - 0.5f;
  float v = bits_to_unit(unif_bits(ch.z, ch.w, p));
  float u_sh = 0.5f - fabsf(u);
  float kf = floorf(fmaf(rc.two_a / u_sh + rc.bb, u, rc.lam) + (float)0.43);
  kf_out = kf;
  if ((u_sh >= (float)0.07) && (v <= rc.v_r)) return true;          // accept1
  if ((kf < 0.0f) || ((u_sh < (float)0.013) && (v > u_sh))) return false; // reject
  float sv = xla_logf((v * rc.inv_alpha) / ((rc.aa / (u_sh * u_sh)) + rc.bb));
  float tv = fmaf(kf, rc.log_lam, rc.neg_lam) - xla_lgammaf_pos(kf + 1.0f);
  return sv <= tv;                                                  // accept2
}

// lam_rejection per lax.select: knuth-masked (lam<10 or lam==0) -> 1e5f
__device__ __forceinline__ float lam_rejection(float uimg) {
  float lam = 100000.0f;
  if (uimg != 0.0f) {
    float l = 1.0f / uimg;
    if (!(l < 10.0f)) lam = l;
  }
  return lam;
}

// ---------------- prologue: subkey chains + G slot ---------------------------
__global__ void chain_init(uint32_t* __restrict__ ws) {
  if (blockIdx.x == 0) {
    if (threadIdx.x != 0) return;
    ws[G_SLOT] = 0u;
    uint32_t r0 = 0u, r1 = 42u;  // jax.random.key(42) -> (0,42)
    for (int j = 0; j < KN_MAX; ++j) {
      uint32_t s0, s1, n0, n1;
      tf2x32(r0, r1, 0u, 1u, s0, s1);
      tf2x32(r0, r1, 0u, 0u, n0, n1);
      ws[2 * j] = s0; ws[2 * j + 1] = s1;
      r0 = n0; r1 = n1;
    }
  } else {
    if (threadIdx.x != 0) return;
    uint32_t c0 = 0u, c1 = 42u;
    for (int j = 0; j < RJ_MAX; ++j) {
      uint32_t a0, a1, b0, b1, n0, n1;
      tf2x32(c0, c1, 0u, 1u, a0, a1);
      tf2x32(c0, c1, 0u, 2u, b0, b1);
      tf2x32(c0, c1, 0u, 0u, n0, n1);
      uint32_t base = KN_MAX * 2 + 4 * j;
      ws[base + 0] = a0; ws[base + 1] = a1; ws[base + 2] = b0; ws[base + 3] = b1;
      c0 = n0; c1 = n1;
    }
  }
}

// ---------------- pass 1: G = max first-accept over ALL (T,N) positions ------
// Flattened per-lane (t,j) automaton: every active lane does one rej_step per
// wave step (no per-t max-lane lockstep).
__global__ void __launch_bounds__(256)
rej_gmax(const float* __restrict__ img, const uint32_t* __restrict__ ws_chains,
         uint32_t* __restrict__ gmax) {
  __shared__ uint4 rj4[RJ_MAX];
  __shared__ uint32_t red[256];
  for (int i = threadIdx.x; i < RJ_MAX; i += 256) {
    uint32_t b = KN_MAX * 2 + 4 * i;
    rj4[i] = make_uint4(ws_chains[b], ws_chains[b + 1],
                        ws_chains[b + 2], ws_chains[b + 3]);
  }
  __syncthreads();

  int n = blockIdx.x * 256 + threadIdx.x;
  uint32_t mymax = 1;
  if (n < N_PIX) {
    RejConst rc = make_rej(lam_rejection(img[n]));
    uint32_t p = (uint32_t)n;
    int t = 0, j = 0;
    while (t < T_WIN) {
      float kf;
      bool acc = rej_step4(rc, rj4[j], p, kf);
      if (acc) {
        uint32_t fa = (uint32_t)(j + 1);
        if (fa > mymax) mymax = fa;
        ++t; p += N_PIX; j = 0;
      } else if (++j >= RJ_MAX) {       // safety cap (never hit)
        mymax = RJ_MAX;
        ++t; p += N_PIX; j = 0;
      }
    }
  }
  red[threadIdx.x] = mymax;
  __syncthreads();
  for (int s2 = 128; s2 > 0; s2 >>= 1) {
    if ((int)threadIdx.x < s2) {
      uint32_t o = red[threadIdx.x + s2];
      if (o > red[threadIdx.x]) red[threadIdx.x] = o;
    }
    __syncthreads();
  }
  if (threadIdx.x == 0) atomicMax((unsigned int*)gmax, red[0]);
}

// ---------------- pass 2: one thread per pixel, flattened --------------------
__global__ void __launch_bounds__(256)
spike_main(const float* __restrict__ img, int* __restrict__ out,
           const uint32_t* __restrict__ chains) {
  __shared__ uint2 kn2[KN_MAX];
  __shared__ uint4 rj4[RJ_MAX];
  __shared__ int shG;
  for (int i = threadIdx.x; i < KN_MAX; i += 256)
    kn2[i] = make_uint2(chains[2 * i], chains[2 * i + 1]);
  for (int i = threadIdx.x; i < RJ_MAX; i += 256) {
    uint32_t b = KN_MAX * 2 + 4 * i;
    rj4[i] = make_uint4(chains[b], chains[b + 1], chains[b + 2], chains[b + 3]);
  }
  if (threadIdx.x == 0) shG = (int)chains[G_SLOT];
  __syncthreads();
  const int G = shG;

  int n = blockIdx.x * 256 + threadIdx.x;
  if (n >= N_PIX) return;
  float uimg = img[n];
  unsigned long long bm0 = 0ull, bm1 = 0ull;  // spike bitmap: bit (s-1), s in [1,100]

  if (uimg != 0.0f) {
    float lam = 1.0f / uimg;
    if (lam < 10.0f) {
      // ---- Knuth, flattened: one draw per step, per-lane (t,j,k,lp,s) -----
      float neg_lam = -lam;
      uint32_t p = (uint32_t)n;
      int s = 0, k = 0, j = 0;
      float lp = 0.0f;
      while (true) {
        uint2 sk = kn2[j];
        float u = bits_to_unit(unif_bits(sk.x, sk.y, p));
        ++k; ++j;
        lp = lp + xla_logf(u);
        if (lp <= neg_lam || j >= KN_MAX) {   // this t resolved
          int iv = k - 1;
          if (iv == 0) iv = 1;                // nz & interval==0 -> 1
          s += iv;
          if (s > T_WIN) break;               // integer cumsum <=100 exact
          if (s <= 64) bm0 |= 1ull << (s - 1); else bm1 |= 1ull << (s - 65);
          p += N_PIX; j = 0; k = 0; lp = 0.0f;
          // t advance folded into p; count via s-independent check:
          if (p >= (uint32_t)T_WIN * (uint32_t)N_PIX) break;
        }
      }
    } else {
      // ---- Rejection: last accept in [0,G) == first accept scanning DOWN --
      RejConst rc = make_rej(lam);
      uint32_t p = (uint32_t)n;
      int s = 0, j = G - 1, t = 0;
      while (t < T_WIN) {
        float kf;
        bool acc = rej_step4(rc, rj4[j], p, kf);
        if (acc) {
          int iv = (kf >= 102.0f) ? 102 : (int)kf;  // values >100 all dead
          if (iv == 0) iv = 1;
          s += iv;
          if (s > T_WIN) break;
          if (s <= 64) bm0 |= 1ull << (s - 1); else bm1 |= 1ull << (s - 65);
          ++t; p += N_PIX; j = G - 1;
        } else if (--j < 0) {
          break;  // impossible: G covers every position's first accept
        }
      }
    }
  }

  // Column write: int32 0/1 (bool output); coalesced; zero-fills poisoned d_out.
  size_t base = (size_t)n;
  for (int t = 0; t < 64; ++t)
    out[base + (size_t)t * N_PIX] = (int)((bm0 >> t) & 1ull);
  for (int t = 64; t < T_WIN; ++t)
    out[base + (size_t)t * N_PIX] = (int)((bm1 >> (t - 64)) & 1ull);
}

extern "C" void kernel_launch(void* const* d_in, const int* in_sizes, int n_in,
                              void* d_out, int out_size, void* d_ws, size_t ws_size,
                              hipStream_t stream) {
  const float* img = (const float*)d_in[0];
  int* out = (int*)d_out;
  uint32_t* ws = (uint32_t*)d_ws;  // needs 1540 B
  hipLaunchKernelGGL(chain_init, dim3(2), dim3(64), 0, stream, ws);
  hipLaunchKernelGGL(rej_gmax, dim3(N_PIX / 256), dim3(256), 0, stream,
                     img, ws, ws + G_SLOT);
  hipLaunchKernelGGL(spike_main, dim3(N_PIX / 256), dim3(256), 0, stream,
                     img, out, ws);
}

// Round 7
// 1243.424 us; speedup vs baseline: 3.2489x; 1.3153x over previous
//
#include <hip/hip_runtime.h>
#include <math.h>
#include <stdint.h>

// Keep compiler contraction OFF globally: the ONLY fusions are my explicit
// fmaf() calls, which model LLVM's contract-FMF fusion on the XLA CPU host.
#pragma clang fp contract(off)

#define N_PIX 802816          // 16*1*224*224 = 512*1568
#define T_WIN 100
#define KN_MAX 96             // Knuth subkey chain length
#define RJ_MAX 48             // rejection subkey chain length (G ~ 10)
#define G_SLOT (KN_MAX * 2 + RJ_MAX * 4)   // ws u32 index of global max-iter
#define TAB_BASE 98000        // lgamma table covers kf in [TAB_BASE, TAB_BASE+TAB_N)
#define TAB_N    4096
#define TAB_WS   (G_SLOT + 1)
#define WS_NEEDED ((TAB_WS + TAB_N) * 4)

// ---------------- threefry2x32 (JAX rotation/injection schedule) -------------
__device__ __forceinline__ void tf2x32(uint32_t k0, uint32_t k1,
                                       uint32_t x0, uint32_t x1,
                                       uint32_t &o0, uint32_t &o1) {
  uint32_t ks2 = k0 ^ k1 ^ 0x1BD11BDAu;
  x0 += k0; x1 += k1;
#define TF_R(r) { x0 += x1; x1 = (x1 << (r)) | (x1 >> (32 - (r))); x1 ^= x0; }
  TF_R(13) TF_R(15) TF_R(26) TF_R(6)
  x0 += k1;  x1 += ks2 + 1u;
  TF_R(17) TF_R(29) TF_R(16) TF_R(24)
  x0 += ks2; x1 += k0 + 2u;
  TF_R(13) TF_R(15) TF_R(26) TF_R(6)
  x0 += k0;  x1 += k1 + 3u;
  TF_R(17) TF_R(29) TF_R(16) TF_R(24)
  x0 += k1;  x1 += ks2 + 4u;
  TF_R(13) TF_R(15) TF_R(26) TF_R(6)
  x0 += ks2; x1 += k0 + 5u;
#undef TF_R
  o0 = x0; o1 = x1;
}

// Partitionable random_bits, 32-bit: hash (hi=0, lo=p), fold bits1 ^ bits2.
__device__ __forceinline__ uint32_t unif_bits(uint32_t s0, uint32_t s1, uint32_t p) {
  uint32_t a, b;
  tf2x32(s0, s1, 0u, p, a, b);
  return a ^ b;
}

__device__ __forceinline__ float bits_to_unit(uint32_t bits) {
  return __uint_as_float(0x3f800000u | (bits >> 9)) - 1.0f;
}

// ---------------- XLA CPU f32 log (GenerateVF32Log / Eigen plog), with
// contract-FMF fusion exactly as verified in round 5. -------------------------
__device__ __forceinline__ float xla_logf(float xin) {
#pragma clang fp contract(off)
  if (xin == 0.0f) return __uint_as_float(0xff800000u);           // -inf
  if (!(xin > 0.0f)) return __uint_as_float(0x7fc00000u);         // nan
  float x = fmaxf(xin, __uint_as_float(0x00800000u));             // flush denorm
  uint32_t ib = __float_as_uint(x);
  float e = (float)((int)(ib >> 23) - 126);                       // cvt(E-127)+1
  ib = (ib & 0x007fffffu) | 0x3f000000u;                          // [0.5,1)
  x = __uint_as_float(ib);
  float tmp = 0.0f, eadj = 0.0f;
  if (x < (float)0.707106781186547524) { tmp = x; eadj = 1.0f; }
  x = x - 1.0f;
  e = e - eadj;
  x = x + tmp;
  float x2 = x * x;
  float x3 = x2 * x;
  float y  = fmaf((float)7.0376836292e-2,  x, (float)-1.1514610310e-1);
  float y1 = fmaf((float)-1.2420140846e-1, x, (float)1.4249322787e-1);
  float y2 = fmaf((float)2.0000714765e-1,  x, (float)-2.4999993993e-1);
  y  = fmaf(y,  x, (float)1.1676998740e-1);
  y1 = fmaf(y1, x, (float)-1.6668057665e-1);
  y2 = fmaf(y2, x, (float)3.3333331174e-1);
  y  = fmaf(y, x3, y1);
  y  = fmaf(y, x3, y2);
  float eq1 = e * (float)-2.12194440e-4;   // standalone mul
  y = fmaf(y, x3, eq1);                    // fadd(mul,mul): operand-0 fuses
  x = fmaf(-x2, 0.5f, x);                  // fsub(x, mul) -> fnmadd
  x = x + y;                               // add of two fma results
  x = fmaf(e, (float)0.693359375, x);      // fadd(x, mul) -> fma
  return x;
}

// XLA EmitLog1p: |x| < 1e-4 ? fma(-0.5,x,1)*x : log(x+1)
__device__ __forceinline__ float xla_log1pf(float w) {
#pragma clang fp contract(off)
  if (fabsf(w) < (float)1e-4) return fmaf(-0.5f, w, 1.0f) * w;
  return xla_logf(w + 1.0f);
}

// XLA Lgamma (Lanczos g=7), non-reflection branch (x >= 1 in all live uses).
__device__ __forceinline__ float xla_lgammaf_pos(float x) {
#pragma clang fp contract(off)
  const float kBase = (float)0.99999999999980993227684700473478;
  const float c0 = (float)676.520368121885098567009190444019;
  const float c1 = (float)-1259.13921672240287047156078755283;
  const float c2 = (float)771.3234287776530788486528258894;
  const float c3 = (float)-176.61502916214059906584551354;
  const float c4 = (float)12.507343278686904814458936853;
  const float c5 = (float)-0.13857109526572011689554707;
  const float c6 = (float)9.984369578019570859563e-6;
  const float c7 = (float)1.50563273514931155834e-7;
  const float kLogSqrtTwoPi = (float)0.91893853320467274178032973640562;
  const float kGPlusHalf = 7.5f;
  const float kLogGPlusHalf = (float)2.0149030205422647065; // log(7.5)
  float z = x - 1.0f;
  float sum = kBase;
  sum = sum + c0 / ((z + 0.0f) + 1.0f);
  sum = sum + c1 / ((z + 1.0f) + 1.0f);
  sum = sum + c2 / ((z + 2.0f) + 1.0f);
  sum = sum + c3 / ((z + 3.0f) + 1.0f);
  sum = sum + c4 / ((z + 4.0f) + 1.0f);
  sum = sum + c5 / ((z + 5.0f) + 1.0f);
  sum = sum + c6 / ((z + 6.0f) + 1.0f);
  sum = sum + c7 / ((z + 7.0f) + 1.0f);
  float t = kGPlusHalf + z;
  float log_t = kLogGPlusHalf + xla_log1pf(z / kGPlusHalf);
  float log_y = fmaf((z + 0.5f) - t / log_t, log_t, kLogSqrtTwoPi) + xla_logf(sum);
  return log_y;
}

// ---------------- rejection sampler shared pieces ----------------------------
struct RejConst {
  float lam, neg_lam, log_lam, aa, bb, inv_alpha, v_r, two_a;
};

__device__ __forceinline__ RejConst make_rej(float lam) {
  RejConst rc;
  rc.lam = lam;
  rc.neg_lam = -lam;
  rc.log_lam = xla_logf(lam);
  float sq = (float)sqrt((double)lam);                  // CR f32 sqrt
  rc.bb = fmaf(2.53f, sq, (float)0.931);
  rc.aa = fmaf((float)0.02483, rc.bb, (float)-0.059);
  rc.inv_alpha = (float)1.1239 + (float)1.1328 / (rc.bb - (float)3.4);
  rc.v_r = (float)0.9277 - (float)3.6224 / (rc.bb - 2.0f);
  rc.two_a = 2.0f * rc.aa;
  return rc;
}

// One rejection iteration (full lgamma) -- byte-identical to round 5/6.
__device__ __forceinline__ bool rej_step4(const RejConst& rc, uint4 ch,
                                          uint32_t p, float& kf_out) {
  float u = bits_to_unit(unif_bits(ch.x, ch.y, p)) - 0.5f;
  float v = bits_to_unit(unif_bits(ch.z, ch.w, p));
  float u_sh = 0.5f - fabsf(u);
  float kf = floorf(fmaf(rc.two_a / u_sh + rc.bb, u, rc.lam) + (float)0.43);
  kf_out = kf;
  if ((u_sh >= (float)0.07) && (v <= rc.v_r)) return true;          // accept1
  if ((kf < 0.0f) || ((u_sh < (float)0.013) && (v > u_sh))) return false; // reject
  float sv = xla_logf((v * rc.inv_alpha) / ((rc.aa / (u_sh * u_sh)) + rc.bb));
  float tv = fmaf(kf, rc.log_lam, rc.neg_lam) - xla_lgammaf_pos(kf + 1.0f);
  return sv <= tv;                                                  // accept2
}

// ---------------- prologue: subkey chains + lgamma table ---------------------
__global__ void chain_init(uint32_t* __restrict__ ws, int build_table) {
  if (blockIdx.x == 0) {
    if (threadIdx.x != 0) return;
    ws[G_SLOT] = 0u;
    uint32_t r0 = 0u, r1 = 42u;  // jax.random.key(42) -> (0,42)
    for (int j = 0; j < KN_MAX; ++j) {
      uint32_t s0, s1, n0, n1;
      tf2x32(r0, r1, 0u, 1u, s0, s1);
      tf2x32(r0, r1, 0u, 0u, n0, n1);
      ws[2 * j] = s0; ws[2 * j + 1] = s1;
      r0 = n0; r1 = n1;
    }
  } else if (blockIdx.x == 1) {
    if (threadIdx.x != 0) return;
    uint32_t c0 = 0u, c1 = 42u;
    for (int j = 0; j < RJ_MAX; ++j) {
      uint32_t a0, a1, b0, b1, n0, n1;
      tf2x32(c0, c1, 0u, 1u, a0, a1);
      tf2x32(c0, c1, 0u, 2u, b0, b1);
      tf2x32(c0, c1, 0u, 0u, n0, n1);
      uint32_t base = KN_MAX * 2 + 4 * j;
      ws[base + 0] = a0; ws[base + 1] = a1; ws[base + 2] = b0; ws[base + 3] = b1;
      c0 = n0; c1 = n1;
    }
  } else if (build_table) {
    int i = (blockIdx.x - 2) * 256 + threadIdx.x;   // 16 blocks x 256 = TAB_N
    if (i < TAB_N) {
      float kf = (float)(TAB_BASE + i);             // exact (< 2^24)
      ws[TAB_WS + i] = __float_as_uint(xla_lgammaf_pos(kf + 1.0f));
    }
  }
}

// ---------------- pass 1: G = max first-accept over ALL (T,N) positions ------
// Block=512. Deterministic ballot compaction: masked (lam=1e5) pixels to lanes
// [0,nMasked), true-rejection pixels to the back waves. Masked waves use the
// LDS lgamma table in accept2 (rare out-of-range fallback).
__global__ void __launch_bounds__(512)
rej_gmax(const float* __restrict__ img, const uint32_t* __restrict__ ws,
         uint32_t* __restrict__ gmax, int use_table) {
  __shared__ uint4 rj4[RJ_MAX];
  __shared__ float lgtab[TAB_N];
  __shared__ int waveRej[8];
  __shared__ unsigned short order[512];
  __shared__ uint32_t red[512];

  const int tid = threadIdx.x;
  for (int i = tid; i < RJ_MAX; i += 512) {
    uint32_t b = KN_MAX * 2 + 4 * i;
    rj4[i] = make_uint4(ws[b], ws[b + 1], ws[b + 2], ws[b + 3]);
  }
  if (use_table)
    for (int i = tid; i < TAB_N; i += 512) lgtab[i] = __uint_as_float(ws[TAB_WS + i]);

  // ---- classify + deterministic compaction ----
  int n0 = blockIdx.x * 512 + tid;
  float uimg0 = img[n0];
  bool isRej = (uimg0 != 0.0f) && !((1.0f / uimg0) < 10.0f);
  int lane = tid & 63, w = tid >> 6;
  unsigned long long bal = __ballot(isRej ? 1 : 0);
  int within = (int)__popcll(bal & ((1ull << lane) - 1ull));
  if (lane == 0) waveRej[w] = (int)__popcll(bal);
  __syncthreads();
  int rejBefore = 0, totalRej = 0;
  for (int i = 0; i < 8; ++i) { int c = waveRej[i]; totalRej += c; if (i < w) rejBefore += c; }
  int nMasked = 512 - totalRej;
  int slot = isRej ? (nMasked + rejBefore + within)
                   : (64 * w - rejBefore) + (lane - within);
  order[slot] = (unsigned short)tid;
  __syncthreads();

  int n = blockIdx.x * 512 + (int)order[tid];
  bool myRej = (tid >= nMasked);
  RejConst rc = make_rej(myRej ? (1.0f / img[n]) : 100000.0f);

  // ---- flattened first-accept automaton ----
  uint32_t mymax = 1;
  {
    uint32_t p = (uint32_t)n;
    int t = 0, j = 0;
    while (t < T_WIN) {
      uint4 ch = rj4[j];
      float u = bits_to_unit(unif_bits(ch.x, ch.y, p)) - 0.5f;
      float v = bits_to_unit(unif_bits(ch.z, ch.w, p));
      float u_sh = 0.5f - fabsf(u);
      float kf = floorf(fmaf(rc.two_a / u_sh + rc.bb, u, rc.lam) + (float)0.43);
      bool acc;
      if ((u_sh >= (float)0.07) && (v <= rc.v_r)) acc = true;
      else if ((kf < 0.0f) || ((u_sh < (float)0.013) && (v > u_sh))) acc = false;
      else {
        float sv = xla_logf((v * rc.inv_alpha) / ((rc.aa / (u_sh * u_sh)) + rc.bb));
        int ki = (int)kf - TAB_BASE;
        float lg;
        if (use_table && ki >= 0 && ki < TAB_N) lg = lgtab[ki];
        else lg = xla_lgammaf_pos(kf + 1.0f);
        float tv = fmaf(kf, rc.log_lam, rc.neg_lam) - lg;
        acc = (sv <= tv);
      }
      if (acc) {
        uint32_t fa = (uint32_t)(j + 1);
        if (fa > mymax) mymax = fa;
        ++t; p += N_PIX; j = 0;
      } else if (++j >= RJ_MAX) {       // safety cap (never hit)
        mymax = RJ_MAX;
        ++t; p += N_PIX; j = 0;
      }
    }
  }
  red[tid] = mymax;
  __syncthreads();
  for (int s2 = 256; s2 > 0; s2 >>= 1) {
    if (tid < s2) {
      uint32_t o = red[tid + s2];
      if (o > red[tid]) red[tid] = o;
    }
    __syncthreads();
  }
  if (tid == 0) atomicMax((unsigned int*)gmax, red[0]);
}

// ---------------- pass 2: one thread per pixel, compacted + flattened --------
__global__ void __launch_bounds__(512)
spike_main(const float* __restrict__ img, int* __restrict__ out,
           const uint32_t* __restrict__ chains) {
  __shared__ uint2 kn2[KN_MAX];
  __shared__ uint4 rj4[RJ_MAX];
  __shared__ int waveRej[8];
  __shared__ unsigned short order[512];
  __shared__ int shG;
  __shared__ ulonglong2 bmsh[512];

  const int tid = threadIdx.x;
  for (int i = tid; i < KN_MAX; i += 512)
    kn2[i] = make_uint2(chains[2 * i], chains[2 * i + 1]);
  for (int i = tid; i < RJ_MAX; i += 512) {
    uint32_t b = KN_MAX * 2 + 4 * i;
    rj4[i] = make_uint4(chains[b], chains[b + 1], chains[b + 2], chains[b + 3]);
  }
  if (tid == 0) shG = (int)chains[G_SLOT];

  // ---- classify + deterministic compaction (same predicate as gmax) ----
  int n0 = blockIdx.x * 512 + tid;
  float uimg0 = img[n0];
  bool isRej = (uimg0 != 0.0f) && !((1.0f / uimg0) < 10.0f);
  int lane = tid & 63, w = tid >> 6;
  unsigned long long bal = __ballot(isRej ? 1 : 0);
  int within = (int)__popcll(bal & ((1ull << lane) - 1ull));
  if (lane == 0) waveRej[w] = (int)__popcll(bal);
  __syncthreads();
  int rejBefore = 0, totalRej = 0;
  for (int i = 0; i < 8; ++i) { int c = waveRej[i]; totalRej += c; if (i < w) rejBefore += c; }
  int nMasked = 512 - totalRej;
  int slot = isRej ? (nMasked + rejBefore + within)
                   : (64 * w - rejBefore) + (lane - within);
  order[slot] = (unsigned short)tid;
  __syncthreads();

  const int G = shG;
  int nl = (int)order[tid];
  int n = blockIdx.x * 512 + nl;
  bool myRej = (tid >= nMasked);
  float uimg = img[n];
  unsigned long long bm0 = 0ull, bm1 = 0ull;  // spike bitmap: bit (s-1), s in [1,100]

  if (myRej) {
    // ---- Rejection: last accept in [0,G) == first accept scanning DOWN ----
    RejConst rc = make_rej(1.0f / uimg);
    uint32_t p = (uint32_t)n;
    int s = 0, j = G - 1, t = 0;
    while (t < T_WIN) {
      float kf;
      bool acc = rej_step4(rc, rj4[j], p, kf);
      if (acc) {
        int iv = (kf >= 102.0f) ? 102 : (int)kf;  // values >100 all dead
        if (iv == 0) iv = 1;
        s += iv;
        if (s > T_WIN) break;
        if (s <= 64) bm0 |= 1ull << (s - 1); else bm1 |= 1ull << (s - 65);
        ++t; p += N_PIX; j = G - 1;
      } else if (--j < 0) {
        break;  // impossible: G covers every position's first accept
      }
    }
  } else if (uimg != 0.0f) {
    // ---- Knuth, flattened: one draw per step, per-lane (t,j,k,lp,s) ----
    float lam = 1.0f / uimg;
    float neg_lam = -lam;
    uint32_t p = (uint32_t)n;
    int s = 0, k = 0, j = 0;
    float lp = 0.0f;
    while (true) {
      uint2 sk = kn2[j];
      float u = bits_to_unit(unif_bits(sk.x, sk.y, p));
      ++k; ++j;
      lp = lp + xla_logf(u);
      if (lp <= neg_lam || j >= KN_MAX) {   // this t resolved
        int iv = k - 1;
        if (iv == 0) iv = 1;                // nz & interval==0 -> 1
        s += iv;
        if (s > T_WIN) break;               // integer cumsum <=100 exact
        if (s <= 64) bm0 |= 1ull << (s - 1); else bm1 |= 1ull << (s - 65);
        p += N_PIX; j = 0; k = 0; lp = 0.0f;
        if (p >= (uint32_t)T_WIN * (uint32_t)N_PIX) break;
      }
    }
  }

  // Stage bitmaps in LDS, then write columns in ORIGINAL pixel order (coalesced).
  ulonglong2 bm; bm.x = bm0; bm.y = bm1;
  bmsh[nl] = bm;
  __syncthreads();
  ulonglong2 b2 = bmsh[tid];
  size_t base = (size_t)(blockIdx.x * 512 + tid);
  for (int t = 0; t < 64; ++t)
    out[base + (size_t)t * N_PIX] = (int)((b2.x >> t) & 1ull);
  for (int t = 64; t < T_WIN; ++t)
    out[base + (size_t)t * N_PIX] = (int)((b2.y >> (t - 64)) & 1ull);
}

extern "C" void kernel_launch(void* const* d_in, const int* in_sizes, int n_in,
                              void* d_out, int out_size, void* d_ws, size_t ws_size,
                              hipStream_t stream) {
  const float* img = (const float*)d_in[0];
  int* out = (int*)d_out;
  uint32_t* ws = (uint32_t*)d_ws;
  int use_table = (ws_size >= (size_t)WS_NEEDED) ? 1 : 0;
  hipLaunchKernelGGL(chain_init, dim3(2 + TAB_N / 256), dim3(256), 0, stream,
                     ws, use_table);
  hipLaunchKernelGGL(rej_gmax, dim3(N_PIX / 512), dim3(512), 0, stream,
                     img, ws, ws + G_SLOT, use_table);
  hipLaunchKernelGGL(spike_main, dim3(N_PIX / 512), dim3(512), 0, stream,
                     img, out, ws);
}